// Round 1
// baseline (591.411 us; speedup 1.0000x reference)
//
#include <hip/hip_runtime.h>
#include <math.h>

// DeepMMD: 3 pairwise kernel matrices (xx, yy, xy) over 4096 samples,
// reduced on the fly to {sum, trace, row-sums, col-sums}.
// Precision plan (threshold = 3.6e-10 abs on outputs ~1.8e-8):
//   - MLP + feature distances + big accumulations: fp64
//   - original-space distances (exponent /2048): fp32
//   - k_x/k_y diagonals handled analytically (hs_i = 2 + delta_i)

#define N_S   4096
#define TILE  64
#define OBK   32     // org-dim K chunk
#define OPAD  68     // org LDS row stride (floats), 16B-aligned, 2-way banks on read
#define FSTR  52     // feats global row stride (50 + 2 zero pad), doubles
#define FBK   26     // feats K chunk
#define FPAD  66     // feats LDS row stride (doubles)

// ---------------- MLP (fp64) : feats_org(8192x256) -> feats(8192x50) ----------------
__global__ __launch_bounds__(64)
void mlp_kernel(const float* __restrict__ X, const float* __restrict__ Y,
                const float* __restrict__ W1, const float* __restrict__ b1,
                const float* __restrict__ W2, const float* __restrict__ b2,
                const float* __restrict__ W3, const float* __restrict__ b3,
                const float* __restrict__ W4, const float* __restrict__ b4,
                double* __restrict__ feats, double* __restrict__ nf,
                float* __restrict__ norg)
{
    __shared__ double sW1[2560];
    __shared__ double sW2[100], sW3[100], sW4[500];
    __shared__ double sb1[10], sb2[10], sb3[10], sb4[50];
    int tid = threadIdx.x;
    for (int i = tid; i < 2560; i += 64) sW1[i] = (double)W1[i];
    for (int i = tid; i < 100; i += 64) { sW2[i] = (double)W2[i]; sW3[i] = (double)W3[i]; }
    for (int i = tid; i < 500; i += 64) sW4[i] = (double)W4[i];
    if (tid < 10) { sb1[tid] = (double)b1[tid]; sb2[tid] = (double)b2[tid]; sb3[tid] = (double)b3[tid]; }
    for (int i = tid; i < 50; i += 64) sb4[i] = (double)b4[i];
    __syncthreads();

    int r = blockIdx.x * 64 + tid;
    const float* xr = (r < N_S) ? (X + (size_t)r * 256) : (Y + (size_t)(r - N_S) * 256);

    double z[10];
#pragma unroll
    for (int j = 0; j < 10; ++j) z[j] = sb1[j];
    double nrm = 0.0;
    for (int k4 = 0; k4 < 256; k4 += 4) {
        float4 xv4 = *(const float4*)(xr + k4);
        double xv[4] = {(double)xv4.x, (double)xv4.y, (double)xv4.z, (double)xv4.w};
#pragma unroll
        for (int u = 0; u < 4; ++u) {
            nrm += xv[u] * xv[u];
#pragma unroll
            for (int j = 0; j < 10; ++j) z[j] += xv[u] * sW1[(k4 + u) * 10 + j];
        }
    }
    // softplus = max(x,0) + log1p(exp(-|x|))  (matches jax.nn.softplus)
#pragma unroll
    for (int j = 0; j < 10; ++j) z[j] = fmax(z[j], 0.0) + log1p(exp(-fabs(z[j])));

    double z2[10];
#pragma unroll
    for (int j = 0; j < 10; ++j) z2[j] = sb2[j];
#pragma unroll
    for (int k = 0; k < 10; ++k)
#pragma unroll
        for (int j = 0; j < 10; ++j) z2[j] += z[k] * sW2[k * 10 + j];
#pragma unroll
    for (int j = 0; j < 10; ++j) z2[j] = fmax(z2[j], 0.0) + log1p(exp(-fabs(z2[j])));

    double z3[10];
#pragma unroll
    for (int j = 0; j < 10; ++j) z3[j] = sb3[j];
#pragma unroll
    for (int k = 0; k < 10; ++k)
#pragma unroll
        for (int j = 0; j < 10; ++j) z3[j] += z2[k] * sW3[k * 10 + j];
#pragma unroll
    for (int j = 0; j < 10; ++j) z3[j] = fmax(z3[j], 0.0) + log1p(exp(-fabs(z3[j])));

    double nrmf = 0.0;
    double* fr = feats + (size_t)r * FSTR;
    for (int j = 0; j < 50; ++j) {
        double f = sb4[j];
#pragma unroll
        for (int k = 0; k < 10; ++k) f += z3[k] * sW4[k * 50 + j];
        nrmf += f * f;
        fr[j] = f;
    }
    fr[50] = 0.0; fr[51] = 0.0;
    nf[r] = nrmf;
    norg[r] = (float)nrm;
}

// ---------------- pairwise kernel-matrix pass ----------------
// Computes one of k_x (symmetric=1), k_y (symmetric=1), k_xy (symmetric=0).
// Accumulates: per-block fp64 sum -> part[bid]; row/col sums -> delta (fp32 atomics,
// signed); trace (xy only) -> fp64 atomic. Diagonal of symmetric matrices excluded.
__global__ __launch_bounds__(256)
void pair_kernel(const float* __restrict__ Ao, const float* __restrict__ Bo,
                 const double* __restrict__ Af, const double* __restrict__ Bf,
                 const float* __restrict__ noA, const float* __restrict__ noB,
                 const double* __restrict__ nfA, const double* __restrict__ nfB,
                 const float* __restrict__ ep, const float* __restrict__ sq,
                 const float* __restrict__ sph,
                 float* __restrict__ delta, double* __restrict__ part,
                 double* __restrict__ trace,
                 float sign, int symmetric)
{
    __shared__ __align__(16) char smem[2 * FBK * FPAD * 8];  // 27456 B, reused per phase

    int tid = threadIdx.x;
    int it = blockIdx.y, jt = blockIdx.x;
    int bid = it * 64 + jt;
    if (symmetric && jt < it) { if (tid == 0) part[bid] = 0.0; return; }
    int i0 = it * TILE, j0 = jt * TILE;
    int tx = tid & 15, ty = tid >> 4;

    float* smA = (float*)smem;               // [OBK][OPAD]
    float* smB = (float*)smem + OBK * OPAD;
    double* smFA = (double*)smem;            // [FBK][FPAD]
    double* smFB = (double*)smem + FBK * FPAD;

    // ---- phase 1: fp32 dot over original 256 dims ----
    float accO[4][4] = {};
    int lr = tid >> 3;            // 0..31
    int lg = (tid & 7) * 4;       // 0,4,..,28
    for (int kb = 0; kb < 256; kb += OBK) {
        __syncthreads();
#pragma unroll
        for (int rr = 0; rr < 64; rr += 32) {
            float4 a = *(const float4*)(Ao + (size_t)(i0 + lr + rr) * 256 + kb + lg);
            smA[(lg + 0) * OPAD + lr + rr] = a.x;
            smA[(lg + 1) * OPAD + lr + rr] = a.y;
            smA[(lg + 2) * OPAD + lr + rr] = a.z;
            smA[(lg + 3) * OPAD + lr + rr] = a.w;
            float4 b = *(const float4*)(Bo + (size_t)(j0 + lr + rr) * 256 + kb + lg);
            smB[(lg + 0) * OPAD + lr + rr] = b.x;
            smB[(lg + 1) * OPAD + lr + rr] = b.y;
            smB[(lg + 2) * OPAD + lr + rr] = b.z;
            smB[(lg + 3) * OPAD + lr + rr] = b.w;
        }
        __syncthreads();
#pragma unroll
        for (int k = 0; k < OBK; ++k) {
            float4 av = *(const float4*)(smA + k * OPAD + 4 * ty);
            float4 bv = *(const float4*)(smB + k * OPAD + 4 * tx);
            float aa[4] = {av.x, av.y, av.z, av.w};
            float bb[4] = {bv.x, bv.y, bv.z, bv.w};
#pragma unroll
            for (int di = 0; di < 4; ++di)
#pragma unroll
                for (int dj = 0; dj < 4; ++dj)
                    accO[di][dj] = fmaf(aa[di], bb[dj], accO[di][dj]);
        }
    }

    // ---- phase 2: fp64 dot over 52 (50+pad) feature dims ----
    double accF[4][4] = {};
    for (int c = 0; c < 52; c += FBK) {
        __syncthreads();
        for (int idx = tid; idx < TILE * FBK; idx += 256) {
            int i = idx / FBK;
            int k = idx - i * FBK;
            smFA[k * FPAD + i] = Af[(size_t)(i0 + i) * FSTR + c + k];
            smFB[k * FPAD + i] = Bf[(size_t)(j0 + i) * FSTR + c + k];
        }
        __syncthreads();
#pragma unroll
        for (int k = 0; k < FBK; ++k) {
            double a0 = smFA[k * FPAD + 4 * ty + 0];
            double a1 = smFA[k * FPAD + 4 * ty + 1];
            double a2 = smFA[k * FPAD + 4 * ty + 2];
            double a3 = smFA[k * FPAD + 4 * ty + 3];
            double b0 = smFB[k * FPAD + 4 * tx + 0];
            double b1 = smFB[k * FPAD + 4 * tx + 1];
            double b2 = smFB[k * FPAD + 4 * tx + 2];
            double b3 = smFB[k * FPAD + 4 * tx + 3];
            accF[0][0] = fma(a0, b0, accF[0][0]); accF[0][1] = fma(a0, b1, accF[0][1]);
            accF[0][2] = fma(a0, b2, accF[0][2]); accF[0][3] = fma(a0, b3, accF[0][3]);
            accF[1][0] = fma(a1, b0, accF[1][0]); accF[1][1] = fma(a1, b1, accF[1][1]);
            accF[1][2] = fma(a1, b2, accF[1][2]); accF[1][3] = fma(a1, b3, accF[1][3]);
            accF[2][0] = fma(a2, b0, accF[2][0]); accF[2][1] = fma(a2, b1, accF[2][1]);
            accF[2][2] = fma(a2, b2, accF[2][2]); accF[2][3] = fma(a2, b3, accF[2][3]);
            accF[3][0] = fma(a3, b0, accF[3][0]); accF[3][1] = fma(a3, b1, accF[3][1]);
            accF[3][2] = fma(a3, b2, accF[3][2]); accF[3][3] = fma(a3, b3, accF[3][3]);
        }
    }

    // ---- epilogue: kernel values + local accumulation ----
    float noi[4], noj[4];
    double nfi[4], nfj[4];
#pragma unroll
    for (int u = 0; u < 4; ++u) {
        noi[u] = noA[i0 + 4 * ty + u];
        noj[u] = noB[j0 + 4 * tx + u];
        nfi[u] = nfA[i0 + 4 * ty + u];
        nfj[u] = nfB[j0 + 4 * tx + u];
    }
    double eps = 1.0 / (1.0 + exp(-(double)ep[0]));
    double sqv = (double)sq[0];  double inv_sq = 1.0 / (sqv * sqv);
    double spv = (double)sph[0]; double inv_sp = 1.0 / (spv * spv);
    const double LOG2E = 1.4426950408889634;
    float  c_o = (float)(inv_sq * LOG2E);   // exponent scale for do (fp32 ok: /2048)
    double c_f = inv_sp * LOG2E;            // exponent scale for d (fp64: /0.005)
    float epsf = (float)eps;
    float omef = (float)(1.0 - eps);

    double bsum = 0.0, trp = 0.0;
    float rowp[4] = {0, 0, 0, 0}, colp[4] = {0, 0, 0, 0};
#pragma unroll
    for (int di = 0; di < 4; ++di) {
#pragma unroll
        for (int dj = 0; dj < 4; ++dj) {
            int gi = i0 + 4 * ty + di, gj = j0 + 4 * tx + dj;
            float  doo = fmaxf(noi[di] + noj[dj] - 2.0f * accO[di][dj], 0.0f);
            double dd  = fmax(nfi[di] + nfj[dj] - 2.0 * accF[di][dj], 0.0);
            float e1 = exp2f(-doo * c_o);
            float e2 = exp2f(-(float)(dd * c_f));
            float kv = e1 * (omef * e2 + epsf);
            if (symmetric && gi == gj) kv = 0.0f;      // diag handled analytically
            if (!symmetric && gi == gj) trp += (double)kv;
            bsum += (double)kv;
            rowp[di] += kv;
            colp[dj] += kv;
        }
    }

    // ---- block reductions (reuse smem) ----
    __syncthreads();
    double* dred = (double*)smem;
    dred[tid] = bsum;
    __syncthreads();
    for (int s = 128; s > 0; s >>= 1) {
        if (tid < s) dred[tid] += dred[tid + s];
        __syncthreads();
    }
    if (tid == 0) part[bid] = (symmetric && it != jt) ? 2.0 * dred[0] : dred[0];
    if (!symmetric && it == jt) {   // block-uniform branch
        __syncthreads();
        dred[tid] = trp;
        __syncthreads();
        for (int s = 128; s > 0; s >>= 1) {
            if (tid < s) dred[tid] += dred[tid + s];
            __syncthreads();
        }
        if (tid == 0) atomicAdd(trace, dred[0]);
    }

    __syncthreads();
    float* red = (float*)smem;  // [64][17]
#pragma unroll
    for (int u = 0; u < 4; ++u) red[(4 * ty + u) * 17 + tx] = rowp[u];
    __syncthreads();
    if (tid < 64) {
        float s = 0.0f;
#pragma unroll
        for (int x = 0; x < 16; ++x) s += red[tid * 17 + x];
        atomicAdd(&delta[i0 + tid], sign * s);
    }
    __syncthreads();
    if (!(symmetric && it == jt)) {  // block-uniform; diag tiles: rows only
#pragma unroll
        for (int u = 0; u < 4; ++u) red[(4 * tx + u) * 17 + ty] = colp[u];
        __syncthreads();
        if (tid < 64) {
            float s = 0.0f;
#pragma unroll
            for (int y = 0; y < 16; ++y) s += red[tid * 17 + y];
            atomicAdd(&delta[j0 + tid], sign * s);
        }
    }
}

// ---------------- final scalar assembly ----------------
__global__ __launch_bounds__(256)
void final_kernel(const float* __restrict__ delta,
                  const double* __restrict__ pXX, const double* __restrict__ pYY,
                  const double* __restrict__ pXY, const double* __restrict__ trace,
                  float* __restrict__ out)
{
    __shared__ double buf[256 * 5];
    int tid = threadIdx.x;
    double sD = 0, sD2 = 0, sXX = 0, sYY = 0, sXY = 0;
    for (int i = tid; i < 4096; i += 256) {
        double d = (double)delta[i];
        sD += d; sD2 += d * d;
        sXX += pXX[i]; sYY += pYY[i]; sXY += pXY[i];
    }
    buf[tid] = sD; buf[256 + tid] = sD2; buf[512 + tid] = sXX;
    buf[768 + tid] = sYY; buf[1024 + tid] = sXY;
    __syncthreads();
    for (int s = 128; s > 0; s >>= 1) {
        if (tid < s) {
            buf[tid] += buf[tid + s];
            buf[256 + tid] += buf[256 + tid + s];
            buf[512 + tid] += buf[512 + tid + s];
            buf[768 + tid] += buf[768 + tid + s];
            buf[1024 + tid] += buf[1024 + tid + s];
        }
        __syncthreads();
    }
    if (tid == 0) {
        double n = (double)N_S;
        double D = n * (n - 1.0);
        double xx = buf[512] / D, yy = buf[768] / D;
        double xy = (buf[1024] - trace[0]) / D;
        double mmd2 = xx - 2.0 * xy + yy;
        // hs_i = 2 + delta_i  (diag of k_x,k_y is exactly 1 each)
        double sumd = buf[0], sumd2 = buf[256];
        double sumh = 2.0 * n + sumd;
        double sumhs2 = 4.0 * n + 4.0 * sumd + sumd2;
        double n3 = n * n * n, n4 = n3 * n;
        double v1 = 4.0 / n3 * sumhs2;
        double v2 = 4.0 / n4 * sumh * sumh;
        double var = v1 - v2 + 1e-8;
        out[0] = (float)mmd2;
        out[1] = (float)var;
    }
}

extern "C" void kernel_launch(void* const* d_in, const int* in_sizes, int n_in,
                              void* d_out, int out_size, void* d_ws, size_t ws_size,
                              hipStream_t stream)
{
    const float* X   = (const float*)d_in[0];
    const float* Y   = (const float*)d_in[1];
    const float* W1  = (const float*)d_in[2];
    const float* b1  = (const float*)d_in[3];
    const float* W2  = (const float*)d_in[4];
    const float* b2  = (const float*)d_in[5];
    const float* W3  = (const float*)d_in[6];
    const float* b3  = (const float*)d_in[7];
    const float* W4  = (const float*)d_in[8];
    const float* b4  = (const float*)d_in[9];
    const float* ep  = (const float*)d_in[10];
    const float* sq  = (const float*)d_in[11];
    const float* sph = (const float*)d_in[12];
    float* out = (float*)d_out;

    char* ws = (char*)d_ws;
    double* feats = (double*)ws;                  // 8192*52*8 = 3407872
    double* nf    = (double*)(ws + 3407872);      // 65536
    float*  norg  = (float*)(ws + 3473408);       // 32768
    float*  delta = (float*)(ws + 3506176);       // 16384
    double* scal  = (double*)(ws + 3522560);      // 64 (scal[0] = trace_xy)
    double* pXX   = (double*)(ws + 3522624);      // 32768
    double* pYY   = (double*)(ws + 3555392);      // 32768
    double* pXY   = (double*)(ws + 3588160);      // 32768

    // zero the accumulators (delta + scal are contiguous)
    hipMemsetAsync(delta, 0, 16384 + 64, stream);

    mlp_kernel<<<128, 64, 0, stream>>>(X, Y, W1, b1, W2, b2, W3, b3, W4, b4,
                                       feats, nf, norg);

    dim3 grid(64, 64);
    // k_x (symmetric, upper triangle, doubled)
    pair_kernel<<<grid, 256, 0, stream>>>(X, X, feats, feats, norg, norg, nf, nf,
                                          ep, sq, sph, delta, pXX, scal, 1.0f, 1);
    // k_y
    pair_kernel<<<grid, 256, 0, stream>>>(Y, Y, feats + (size_t)N_S * FSTR,
                                          feats + (size_t)N_S * FSTR,
                                          norg + N_S, norg + N_S, nf + N_S, nf + N_S,
                                          ep, sq, sph, delta, pYY, scal, 1.0f, 1);
    // k_xy (full)
    pair_kernel<<<grid, 256, 0, stream>>>(X, Y, feats, feats + (size_t)N_S * FSTR,
                                          norg, norg + N_S, nf, nf + N_S,
                                          ep, sq, sph, delta, pXY, scal, -1.0f, 0);

    final_kernel<<<1, 256, 0, stream>>>(delta, pXX, pYY, pXY, scal, out);
}

// Round 2
// 338.500 us; speedup vs baseline: 1.7472x; 1.7472x over previous
//
#include <hip/hip_runtime.h>
#include <math.h>

// DeepMMD, round 2: joint symmetric 8192x8192 pass, 128x128 tiles (2080 blocks).
//  - org-space dot: fp16 hi/lo split (3 products) on v_mfma_f32_32x32x16_f16
//  - feature distance: exact fp32 sum of squared diffs (precision-critical)
//  - e1 = wA * wB * exp2f(2*G*co), wA/wB precomputed per-sample in MLP kernel
//  - reductions: row/col sums -> fp32 atomics on D8[8192]; Sxx/Syy/Sxy/trace fp64 atomics

#define N_S 4096
#define LOG2E 1.4426950408889634

typedef _Float16 v8h __attribute__((ext_vector_type(8)));
typedef float v16f __attribute__((ext_vector_type(16)));

union U16 { uint4 u; v8h h; };

// ---------------- MLP (fp64 internals) -> featsT[52][8192] fp32, wOrg[8192] ----------------
__global__ __launch_bounds__(64)
void mlp_kernel(const float* __restrict__ X, const float* __restrict__ Y,
                const float* __restrict__ W1, const float* __restrict__ b1,
                const float* __restrict__ W2, const float* __restrict__ b2,
                const float* __restrict__ W3, const float* __restrict__ b3,
                const float* __restrict__ W4, const float* __restrict__ b4,
                const float* __restrict__ sq,
                float* __restrict__ featsT, float* __restrict__ wOrg)
{
    __shared__ double sW1[2560];
    __shared__ double sW2[100], sW3[100], sW4[500];
    __shared__ double sb1[10], sb2[10], sb3[10], sb4[50];
    int tid = threadIdx.x;
    for (int i = tid; i < 2560; i += 64) sW1[i] = (double)W1[i];
    for (int i = tid; i < 100; i += 64) { sW2[i] = (double)W2[i]; sW3[i] = (double)W3[i]; }
    for (int i = tid; i < 500; i += 64) sW4[i] = (double)W4[i];
    if (tid < 10) { sb1[tid] = (double)b1[tid]; sb2[tid] = (double)b2[tid]; sb3[tid] = (double)b3[tid]; }
    for (int i = tid; i < 50; i += 64) sb4[i] = (double)b4[i];
    __syncthreads();

    int r = blockIdx.x * 64 + tid;
    const float* xr = (r < N_S) ? (X + (size_t)r * 256) : (Y + (size_t)(r - N_S) * 256);

    double z[10];
#pragma unroll
    for (int j = 0; j < 10; ++j) z[j] = sb1[j];
    double nrm = 0.0;
    for (int k4 = 0; k4 < 256; k4 += 4) {
        float4 xv4 = *(const float4*)(xr + k4);
        double xv[4] = {(double)xv4.x, (double)xv4.y, (double)xv4.z, (double)xv4.w};
#pragma unroll
        for (int u = 0; u < 4; ++u) {
            nrm += xv[u] * xv[u];
#pragma unroll
            for (int j = 0; j < 10; ++j) z[j] += xv[u] * sW1[(k4 + u) * 10 + j];
        }
    }
#pragma unroll
    for (int j = 0; j < 10; ++j) z[j] = fmax(z[j], 0.0) + log1p(exp(-fabs(z[j])));

    double z2[10];
#pragma unroll
    for (int j = 0; j < 10; ++j) z2[j] = sb2[j];
#pragma unroll
    for (int k = 0; k < 10; ++k)
#pragma unroll
        for (int j = 0; j < 10; ++j) z2[j] += z[k] * sW2[k * 10 + j];
#pragma unroll
    for (int j = 0; j < 10; ++j) z2[j] = fmax(z2[j], 0.0) + log1p(exp(-fabs(z2[j])));

    double z3[10];
#pragma unroll
    for (int j = 0; j < 10; ++j) z3[j] = sb3[j];
#pragma unroll
    for (int k = 0; k < 10; ++k)
#pragma unroll
        for (int j = 0; j < 10; ++j) z3[j] += z2[k] * sW3[k * 10 + j];
#pragma unroll
    for (int j = 0; j < 10; ++j) z3[j] = fmax(z3[j], 0.0) + log1p(exp(-fabs(z3[j])));

    for (int j = 0; j < 50; ++j) {
        double f = sb4[j];
#pragma unroll
        for (int k = 0; k < 10; ++k) f += z3[k] * sW4[k * 50 + j];
        featsT[(size_t)j * 8192 + r] = (float)f;   // coalesced across lanes
    }
    featsT[(size_t)50 * 8192 + r] = 0.0f;          // zero pad dims
    featsT[(size_t)51 * 8192 + r] = 0.0f;

    double sqv = (double)sq[0];
    double co = LOG2E / (sqv * sqv);
    wOrg[r] = (float)exp2(-nrm * co);
}

// ---------------- helpers ----------------
__device__ __forceinline__ v8h ldfrag(const uint4* buf, int s, int g) {
    U16 t; t.u = buf[s * 8 + (g ^ (s & 7))];
    return t.h;
}

__device__ __forceinline__ void cvt_split(float4 f0, float4 f1, uint4* hi, uint4* lo) {
    U16 H, L;
    float fv[8] = {f0.x, f0.y, f0.z, f0.w, f1.x, f1.y, f1.z, f1.w};
#pragma unroll
    for (int u = 0; u < 8; ++u) {
        _Float16 h = (_Float16)fv[u];
        H.h[u] = h;
        L.h[u] = (_Float16)(fv[u] - (float)h);
    }
    *hi = H.u; *lo = L.u;
}

// ---------------- joint pairwise pass ----------------
__global__ __launch_bounds__(256, 2)
void pair_kernel(const float* __restrict__ X, const float* __restrict__ Y,
                 const float* __restrict__ featsT, const float* __restrict__ wOrg,
                 const float* __restrict__ ep, const float* __restrict__ sq,
                 const float* __restrict__ sph,
                 float* __restrict__ D8, double* __restrict__ S)
{
    // LDS union: phase F: FA[52][132] (27456) + FB (27456) = 54912
    //            phase A: Ahi/Alo/Bhi/Blo uint4[1024] each = 65536
    //            epilogue: E2band 32x132 f32 (16896) + dred 256 f64 @16896
    __shared__ __align__(16) char smem[65536];

    int tid = threadIdx.x;
    int lane = tid & 63, w = tid >> 6, wr = w >> 1, wc = w & 1;
    int tx = tid & 15, ty = tid >> 4;

    // upper-triangle tile decode
    int L = blockIdx.x, it = 0, span = 64;
    while (L >= span) { L -= span; --span; ++it; }
    int jt = it + L;

    bool sameHalf = (jt < 32) || (it >= 32);
    bool isDiag = (it == jt);
    bool isTrace = (jt == it + 32);
    int region = (jt < 32) ? 0 : ((it >= 32) ? 1 : 2);
    float sgn = sameHalf ? 1.0f : -1.0f;
    int i0 = it * 128, j0 = jt * 128;
    const float* aorg = (it < 32) ? X + (size_t)i0 * 256 : Y + (size_t)(i0 - N_S) * 256;
    const float* borg = (jt < 32) ? X + (size_t)j0 * 256 : Y + (size_t)(j0 - N_S) * 256;

    double epd = (double)ep[0];
    double eps = 1.0 / (1.0 + exp(-epd));
    double sqv = (double)sq[0], spv = (double)sph[0];
    float cf = (float)(LOG2E / (spv * spv));            // feature exponent scale
    float twoco = (float)(2.0 * LOG2E / (sqv * sqv));   // org dot exponent scale
    float epsv = (float)eps, ome = (float)(1.0 - eps);

    // ---- phase F: exact fp32 feature distances (8x8 per thread) ----
    float* FA = (float*)smem;
    float* FB = (float*)(smem + 27456);
    for (int idx = tid; idx < 1664; idx += 256) {    // 52 rows x 32 float4
        int k = idx >> 5, cg = (idx & 31) * 4;
        *(float4*)&FA[k * 132 + cg] = *(const float4*)&featsT[(size_t)k * 8192 + i0 + cg];
        *(float4*)&FB[k * 132 + cg] = *(const float4*)&featsT[(size_t)k * 8192 + j0 + cg];
    }
    __syncthreads();

    float da[8][8];
#pragma unroll
    for (int i = 0; i < 8; ++i)
#pragma unroll
        for (int j = 0; j < 8; ++j) da[i][j] = 0.0f;

    int r0 = ty * 8, c0 = tx * 8;
    for (int k = 0; k < 52; ++k) {
        float4 a0 = *(const float4*)&FA[k * 132 + r0];
        float4 a1 = *(const float4*)&FA[k * 132 + r0 + 4];
        float4 b0 = *(const float4*)&FB[k * 132 + c0];
        float4 b1 = *(const float4*)&FB[k * 132 + c0 + 4];
        float av[8] = {a0.x, a0.y, a0.z, a0.w, a1.x, a1.y, a1.z, a1.w};
        float bv[8] = {b0.x, b0.y, b0.z, b0.w, b1.x, b1.y, b1.z, b1.w};
#pragma unroll
        for (int i = 0; i < 8; ++i)
#pragma unroll
            for (int j = 0; j < 8; ++j) {
                float t = av[i] - bv[j];
                da[i][j] = fmaf(t, t, da[i][j]);
            }
    }
    // d -> e2 (kept in registers through phase A)
#pragma unroll
    for (int i = 0; i < 8; ++i)
#pragma unroll
        for (int j = 0; j < 8; ++j) da[i][j] = exp2f(-da[i][j] * cf);
    __syncthreads();   // FA/FB dead

    // ---- phase A: fp16-split MFMA org dot ----
    uint4* Ahi = (uint4*)smem;
    uint4* Alo = Ahi + 1024;
    uint4* Bhi = Ahi + 2048;
    uint4* Blo = Ahi + 3072;

    v16f acc00{}, acc01{}, acc10{}, acc11{};
    int rs0 = wr * 64 + (lane & 31), rs1 = rs0 + 32;
    int cs0 = wc * 64 + (lane & 31), cs1 = cs0 + 32;

    for (int kb = 0; kb < 256; kb += 64) {
#pragma unroll
        for (int step = 0; step < 4; ++step) {
            int r = step * 32 + (tid >> 3), g8 = tid & 7;
            const float* pa = aorg + (size_t)r * 256 + kb + g8 * 8;
            const float* pb = borg + (size_t)r * 256 + kb + g8 * 8;
            float4 fa0 = *(const float4*)pa, fa1 = *(const float4*)(pa + 4);
            float4 fb0 = *(const float4*)pb, fb1 = *(const float4*)(pb + 4);
            uint4 hi, lo;
            int pg = r * 8 + (g8 ^ (r & 7));          // XOR swizzle, conflict-free b128
            cvt_split(fa0, fa1, &hi, &lo);
            Ahi[pg] = hi; Alo[pg] = lo;
            cvt_split(fb0, fb1, &hi, &lo);
            Bhi[pg] = hi; Blo[pg] = lo;
        }
        __syncthreads();
#pragma unroll
        for (int ks = 0; ks < 4; ++ks) {
            int g = ks * 2 + (lane >> 5);
            v8h ah0 = ldfrag(Ahi, rs0, g), ah1 = ldfrag(Ahi, rs1, g);
            v8h al0 = ldfrag(Alo, rs0, g), al1 = ldfrag(Alo, rs1, g);
            v8h bh0 = ldfrag(Bhi, cs0, g), bh1 = ldfrag(Bhi, cs1, g);
            v8h bl0 = ldfrag(Blo, cs0, g), bl1 = ldfrag(Blo, cs1, g);
            acc00 = __builtin_amdgcn_mfma_f32_32x32x16_f16(al0, bh0, acc00, 0, 0, 0);
            acc00 = __builtin_amdgcn_mfma_f32_32x32x16_f16(ah0, bl0, acc00, 0, 0, 0);
            acc00 = __builtin_amdgcn_mfma_f32_32x32x16_f16(ah0, bh0, acc00, 0, 0, 0);
            acc01 = __builtin_amdgcn_mfma_f32_32x32x16_f16(al0, bh1, acc01, 0, 0, 0);
            acc01 = __builtin_amdgcn_mfma_f32_32x32x16_f16(ah0, bl1, acc01, 0, 0, 0);
            acc01 = __builtin_amdgcn_mfma_f32_32x32x16_f16(ah0, bh1, acc01, 0, 0, 0);
            acc10 = __builtin_amdgcn_mfma_f32_32x32x16_f16(al1, bh0, acc10, 0, 0, 0);
            acc10 = __builtin_amdgcn_mfma_f32_32x32x16_f16(ah1, bl0, acc10, 0, 0, 0);
            acc10 = __builtin_amdgcn_mfma_f32_32x32x16_f16(ah1, bh0, acc10, 0, 0, 0);
            acc11 = __builtin_amdgcn_mfma_f32_32x32x16_f16(al1, bh1, acc11, 0, 0, 0);
            acc11 = __builtin_amdgcn_mfma_f32_32x32x16_f16(ah1, bl1, acc11, 0, 0, 0);
            acc11 = __builtin_amdgcn_mfma_f32_32x32x16_f16(ah1, bh1, acc11, 0, 0, 0);
        }
        __syncthreads();   // frag reads done before next staging overwrite
    }

    // ---- epilogue: 4 row-bands of 32 ----
    float* E2b = (float*)smem;
    double* dred = (double*)(smem + 16896);
    double bsum = 0.0, trsum = 0.0;
    float colacc0 = 0.0f, colacc1 = 0.0f;
    float wb0 = wOrg[j0 + wc * 64 + (lane & 31)];
    float wb1 = wOrg[j0 + wc * 64 + 32 + (lane & 31)];

    auto band_compute = [&](const v16f& aj0, const v16f& aj1, int b) {
#pragma unroll
        for (int reg = 0; reg < 16; ++reg) {
            int rl = 4 * (lane >> 5) + (reg & 3) + 8 * (reg >> 2);
            int trow = 32 * b + rl;
            float wa = wOrg[i0 + trow];
            {
                float G = aj0[reg];
                int cl = wc * 64 + (lane & 31);
                float e2v = E2b[rl * 132 + cl];
                float kv = wa * wb0 * exp2f(G * twoco) * (ome * e2v + epsv);
                if (isDiag && trow == cl) kv = 0.0f;
                if (isTrace && cl == trow) trsum += (double)kv;
                bsum += (double)kv;
                colacc0 += kv;
                E2b[rl * 132 + cl] = kv;
            }
            {
                float G = aj1[reg];
                int cl = wc * 64 + 32 + (lane & 31);
                float e2v = E2b[rl * 132 + cl];
                float kv = wa * wb1 * exp2f(G * twoco) * (ome * e2v + epsv);
                if (isDiag && trow == cl) kv = 0.0f;
                if (isTrace && cl == trow) trsum += (double)kv;
                bsum += (double)kv;
                colacc1 += kv;
                E2b[rl * 132 + cl] = kv;
            }
        }
    };

    for (int b = 0; b < 4; ++b) {
        __syncthreads();            // E2b free
        if (w == b) {               // wave b owns this band's e2 rows
            int br = (ty & 3) * 8;
#pragma unroll
            for (int i = 0; i < 8; ++i) {
                float4 v0 = make_float4(da[i][0], da[i][1], da[i][2], da[i][3]);
                float4 v1 = make_float4(da[i][4], da[i][5], da[i][6], da[i][7]);
                *(float4*)&E2b[(br + i) * 132 + c0] = v0;
                *(float4*)&E2b[(br + i) * 132 + c0 + 4] = v1;
            }
        }
        __syncthreads();
        if (wr == (b >> 1)) {
            if ((b & 1) == 0) band_compute(acc00, acc01, b);
            else              band_compute(acc10, acc11, b);
        }
        __syncthreads();
        if (tid < 32) {             // row sums of kv (written back in place)
            float s = 0.0f;
#pragma unroll
            for (int q = 0; q < 32; ++q) {
                float4 v = *(const float4*)&E2b[tid * 132 + q * 4];
                s += v.x + v.y + v.z + v.w;
            }
            atomicAdd(&D8[i0 + 32 * b + tid], sgn * s);
        }
    }

    // column sums (skip for diagonal tiles: rows already cover both triangles)
    if (!isDiag) {
        atomicAdd(&D8[j0 + wc * 64 + (lane & 31)], sgn * colacc0);
        atomicAdd(&D8[j0 + wc * 64 + 32 + (lane & 31)], sgn * colacc1);
    }

    // block reduce bsum (+ trace)
    __syncthreads();
    dred[tid] = bsum;
    __syncthreads();
    for (int s2 = 128; s2 > 0; s2 >>= 1) {
        if (tid < s2) dred[tid] += dred[tid + s2];
        __syncthreads();
    }
    if (tid == 0) {
        double wgt = (sameHalf && !isDiag) ? 2.0 : 1.0;
        atomicAdd(&S[region], wgt * dred[0]);
    }
    if (isTrace) {
        __syncthreads();
        dred[tid] = trsum;
        __syncthreads();
        for (int s2 = 128; s2 > 0; s2 >>= 1) {
            if (tid < s2) dred[tid] += dred[tid + s2];
            __syncthreads();
        }
        if (tid == 0) atomicAdd(&S[3], dred[0]);
    }
}

// ---------------- final scalar assembly ----------------
__global__ __launch_bounds__(256)
void final_kernel(const float* __restrict__ D8, const double* __restrict__ S,
                  float* __restrict__ out)
{
    __shared__ double buf[512];
    int tid = threadIdx.x;
    double sD = 0, sD2 = 0;
    for (int i = tid; i < 4096; i += 256) {
        double d = (double)D8[i] + (double)D8[i + 4096];
        sD += d; sD2 += d * d;
    }
    buf[tid] = sD; buf[256 + tid] = sD2;
    __syncthreads();
    for (int s = 128; s > 0; s >>= 1) {
        if (tid < s) { buf[tid] += buf[tid + s]; buf[256 + tid] += buf[256 + tid + s]; }
        __syncthreads();
    }
    if (tid == 0) {
        double n = (double)N_S, D = n * (n - 1.0);
        double xx = S[0] / D, yy = S[1] / D, xy = (S[2] - S[3]) / D;
        double mmd2 = xx - 2.0 * xy + yy;
        double sumd = buf[0], sumd2 = buf[256];
        double sumh = 2.0 * n + sumd;                    // hs_i = 2 + delta_i
        double sumhs2 = 4.0 * n + 4.0 * sumd + sumd2;
        double n3 = n * n * n, n4 = n3 * n;
        double var = 4.0 / n3 * sumhs2 - 4.0 / n4 * sumh * sumh + 1e-8;
        out[0] = (float)mmd2;
        out[1] = (float)var;
    }
}

extern "C" void kernel_launch(void* const* d_in, const int* in_sizes, int n_in,
                              void* d_out, int out_size, void* d_ws, size_t ws_size,
                              hipStream_t stream)
{
    const float* X   = (const float*)d_in[0];
    const float* Y   = (const float*)d_in[1];
    const float* W1  = (const float*)d_in[2];
    const float* b1  = (const float*)d_in[3];
    const float* W2  = (const float*)d_in[4];
    const float* b2  = (const float*)d_in[5];
    const float* W3  = (const float*)d_in[6];
    const float* b3  = (const float*)d_in[7];
    const float* W4  = (const float*)d_in[8];
    const float* b4  = (const float*)d_in[9];
    const float* ep  = (const float*)d_in[10];
    const float* sq  = (const float*)d_in[11];
    const float* sph = (const float*)d_in[12];
    float* out = (float*)d_out;

    char* ws = (char*)d_ws;
    float*  featsT = (float*)ws;                      // 52*8192*4 = 1703936
    float*  wOrg   = (float*)(ws + 1703936);          // 32768
    float*  D8     = (float*)(ws + 1736704);          // 32768
    double* S      = (double*)(ws + 1769472);         // 32 (Sxx, Syy, Sxy, trace)

    hipMemsetAsync(D8, 0, 32768 + 32, stream);

    mlp_kernel<<<128, 64, 0, stream>>>(X, Y, W1, b1, W2, b2, W3, b3, W4, b4,
                                       sq, featsT, wOrg);

    pair_kernel<<<2080, 256, 0, stream>>>(X, Y, featsT, wOrg, ep, sq, sph, D8, S);

    final_kernel<<<1, 256, 0, stream>>>(D8, S, out);
}